// Round 6
// baseline (37.427 us; speedup 1.0000x reference)
//
#include <hip/hip_runtime.h>

// LocalDE: im2col patches (C=3,K=3 -> D=27) then all upper-triangular
// pairwise products (378) per position. Output [B*L, 378] fp32, 186 MB.
// R6: zero-LDS row-broadcast scheme. Theory: R4 was LDS-gather-bound
// (13.5 ds_read_b32 wave-instrs/position on the single CU LDS pipe ~=
// 120-160 cyc/pos > 135 cyc/pos store budget). Here lane j owns patch
// element p[j] in a VGPR (loaded direct from global; x is L2-resident),
// row i's broadcast p[i] comes via v_readlane (compile-time lane index,
// loop fully unrolled), and each row's dword store uses a compile-time
// immediate offset (s_i - i)*4 off one per-lane base address.
// Two positions per wave (lanes 0-31 / 32-63). No LDS, no barriers.

#define B_    32
#define C_    3
#define H_    64
#define W_    64
#define HOUT  62
#define WOUT  62
#define L_    (HOUT * WOUT)   // 3844
#define D_    27
#define NPAIR 378             // D*(D+1)/2
#define NPOS  (B_ * L_)       // 123008, divisible by 8

__global__ __launch_bounds__(256) void localde_kernel(
    const float* __restrict__ x, float* __restrict__ out) {
  const int tid  = threadIdx.x;
  const int lane = tid & 63;
  const int wv   = tid >> 6;
  const int half = lane >> 5;          // which of the wave's 2 positions
  const int j    = lane & 31;          // patch element this lane owns
  const int jj   = (j < D_) ? j : (D_ - 1);   // clamp lanes 27..31 (unused)

  // This lane's position index.
  const int pos = (blockIdx.x * 4 + wv) * 2 + half;
  int b  = pos / L_;
  int l  = pos - b * L_;
  int oh = l / WOUT;
  int ow = l - oh * WOUT;

  // Patch element jj -> (c, ki, kj), channel-major (matches nn.Unfold).
  int c  = jj / 9;
  int r  = jj - c * 9;
  int ki = r / 3;
  int kj = r - ki * 3;

  const float pj  = x[((b * C_ + c) * H_ + oh + ki) * W_ + ow + kj];
  const int   pjb = __float_as_int(pj);

  // Lane's column base: out[pos*378 + j]; row i lands at +(s_i - i) floats,
  // a compile-time immediate per unrolled row.
  float* const base = out + (size_t)pos * NPAIR + j;

#pragma unroll
  for (int i = 0; i < D_; ++i) {
    const int s = i * D_ - (i * (i - 1)) / 2;   // row start in packed triu
    int lo = __builtin_amdgcn_readlane(pjb, i);        // p[i] of position 0
    int hi = __builtin_amdgcn_readlane(pjb, 32 + i);   // p[i] of position 1
    float pi = __int_as_float(half ? hi : lo);
    if (j >= i && j < D_) base[s - i] = pi * pj;
  }
}

extern "C" void kernel_launch(void* const* d_in, const int* in_sizes, int n_in,
                              void* d_out, int out_size, void* d_ws, size_t ws_size,
                              hipStream_t stream) {
  const float* x = (const float*)d_in[0];
  float* out = (float*)d_out;
  const int grid = NPOS / 8;  // 15376 blocks, 8 positions (4 waves) each
  localde_kernel<<<grid, 256, 0, stream>>>(x, out);
}

// Round 7
// 34.693 us; speedup vs baseline: 1.0788x; 1.0788x over previous
//
#include <hip/hip_runtime.h>

// LocalDE: im2col patches (C=3,K=3 -> D=27), all triu pairwise products
// (378) per position. Output [B*L, 378] fp32, 186 MB. R7: row-strip tiles.
// 1 wave per (b,oh) output row: stage x[b,:,oh:oh+3,:] once (576 floats,
// coalesced), then 31 pair-iters x 3 float4 stores fed by LDS gathers with
// HOISTED per-lane offsets (closed-form triangular root, no table). No
// barriers in the store loop, no global reads in steady state. LDS stride
// 67 words => bank(d)=d, all 27 patch elems in distinct banks.

#define B_    32
#define C_    3
#define H_    64
#define W_    64
#define HOUT  62
#define WOUT  62
#define L_    (HOUT * WOUT)   // 3844
#define D_    27
#define NPAIR 378             // D*(D+1)/2
#define XSS   67              // LDS row stride in words

typedef float f32x4 __attribute__((ext_vector_type(4)));

__global__ __launch_bounds__(64) void localde_kernel(
    const float* __restrict__ x, float* __restrict__ out) {
  __shared__ float xs[9 * XSS];   // 2412 B: rows (3c+ki) x 64 cols

  const int lane = threadIdx.x;
  const int bo = blockIdx.x;      // b*62 + oh
  const int b  = bo / HOUT;
  const int oh = bo - b * HOUT;

  // Stage x[b, :, oh:oh+3, 0:64] -> xs (9 rows x 16 float4 = 144 loads).
#pragma unroll
  for (int t0 = 0; t0 < 3; ++t0) {
    int t = lane + (t0 << 6);
    if (t < 144) {
      int row = t >> 4;                 // 3c+ki, 0..8
      int c4  = (t & 15) << 2;          // col
      const float* src =
          x + (((size_t)(b * C_ + row / 3) * H_) + oh + row % 3) * W_ + c4;
      f32x4 v = *(const f32x4*)src;
      float* dst = &xs[row * XSS + c4];
      dst[0] = v[0]; dst[1] = v[1]; dst[2] = v[2]; dst[3] = v[3];
    }
  }
  __syncthreads();

  // Hoist per-lane operand LDS byte offsets: 3 chunks x 4 elems x 2 ops.
  // Chunk t covers float4 index q = lane + 64t of the 189 float4 spanning
  // 2 consecutive positions (756 floats); element e>=378 belongs to the
  // second position = next column = +1 word in xs.
  int offA[3][4], offB[3][4];
#pragma unroll
  for (int t = 0; t < 3; ++t) {
#pragma unroll
    for (int k = 0; k < 4; ++k) {
      int e = 4 * (lane + (t << 6)) + k;
      if (e > 755) e = 755;             // clamp idle lanes (61-63, t=2)
      int pos = (e >= NPAIR) ? 1 : 0;
      int ee = e - pos * NPAIR;
      // triangular root: largest i with 27i - i(i-1)/2 <= ee (exact at
      // boundaries: 3025-8*s_i = (55-2i)^2, perfect square).
      int i = (int)((55.0f - sqrtf((float)(3025 - 8 * ee))) * 0.5f);
      int j = ee - (27 * i - ((i * (i - 1)) >> 1)) + i;
      offA[t][k] = ((i / 3) * XSS + (i % 3) + pos) * 4;
      offB[t][k] = ((j / 3) * XSS + (j % 3) + pos) * 4;
    }
  }

  float* orow = out + (size_t)(b * L_ + oh * WOUT) * NPAIR;
  const char* xsb = (const char*)xs;

  for (int s = 0; s < WOUT / 2; ++s) {        // 31 position-pairs
    f32x4* op = (f32x4*)(orow + s * (2 * NPAIR));
    const int so = s * 8;                     // +2 columns per pair
#pragma unroll
    for (int t = 0; t < 3; ++t) {
      if (t < 2 || lane < 61) {
        f32x4 v;
#pragma unroll
        for (int k = 0; k < 4; ++k) {
          float a = *(const float*)(xsb + offA[t][k] + so);
          float c = *(const float*)(xsb + offB[t][k] + so);
          v[k] = a * c;
        }
        op[lane + (t << 6)] = v;
      }
    }
  }
}

extern "C" void kernel_launch(void* const* d_in, const int* in_sizes, int n_in,
                              void* d_out, int out_size, void* d_ws, size_t ws_size,
                              hipStream_t stream) {
  const float* x = (const float*)d_in[0];
  float* out = (float*)d_out;
  localde_kernel<<<B_ * HOUT, 64, 0, stream>>>(x, out);  // 1984 one-wave blocks
}

// Round 8
// 34.430 us; speedup vs baseline: 1.0870x; 1.0076x over previous
//
#include <hip/hip_runtime.h>

// LocalDE: im2col patches (C=3,K=3 -> D=27), all triu pairwise products
// (378) per position. Output [B*L, 378] fp32, 186 MB. R8: R7 row-strip
// structure, single-variable change: 256-thread blocks (4 independent
// waves = 4 (b,oh) rows per block, 496 blocks) to match the shape class
// of the 6.9 TB/s harness fill kernels. Discriminator for the
// fixed-overhead-vs-block-shape hypothesis.

#define B_    32
#define C_    3
#define H_    64
#define W_    64
#define HOUT  62
#define WOUT  62
#define L_    (HOUT * WOUT)   // 3844
#define D_    27
#define NPAIR 378             // D*(D+1)/2
#define XSS   67              // LDS row stride in words

typedef float f32x4 __attribute__((ext_vector_type(4)));

__global__ __launch_bounds__(256) void localde_kernel(
    const float* __restrict__ x, float* __restrict__ out) {
  __shared__ float xs[4][9 * XSS];   // per-wave strip: rows (3c+ki) x 64 cols

  const int lane = threadIdx.x & 63;
  const int wv   = threadIdx.x >> 6;
  const int bo = blockIdx.x * 4 + wv;  // b*62 + oh, one row per wave
  const int b  = bo / HOUT;
  const int oh = bo - b * HOUT;

  // Stage x[b, :, oh:oh+3, 0:64] -> xs[wv] (9 rows x 16 float4 = 144 loads).
#pragma unroll
  for (int t0 = 0; t0 < 3; ++t0) {
    int t = lane + (t0 << 6);
    if (t < 144) {
      int row = t >> 4;                 // 3c+ki, 0..8
      int c4  = (t & 15) << 2;          // col
      const float* src =
          x + (((size_t)(b * C_ + row / 3) * H_) + oh + row % 3) * W_ + c4;
      f32x4 v = *(const f32x4*)src;
      float* dst = &xs[wv][row * XSS + c4];
      dst[0] = v[0]; dst[1] = v[1]; dst[2] = v[2]; dst[3] = v[3];
    }
  }
  __builtin_amdgcn_s_waitcnt(0);        // vmcnt(0)+lgkmcnt(0): own-wave staging
  __builtin_amdgcn_wave_barrier();      // no cross-wave LDS sharing -> no s_barrier

  // Hoist per-lane operand LDS byte offsets: 3 chunks x 4 elems x 2 ops.
  int offA[3][4], offB[3][4];
#pragma unroll
  for (int t = 0; t < 3; ++t) {
#pragma unroll
    for (int k = 0; k < 4; ++k) {
      int e = 4 * (lane + (t << 6)) + k;
      if (e > 755) e = 755;             // clamp idle lanes (61-63, t=2)
      int pos = (e >= NPAIR) ? 1 : 0;
      int ee = e - pos * NPAIR;
      int i = (int)((55.0f - sqrtf((float)(3025 - 8 * ee))) * 0.5f);
      int j = ee - (27 * i - ((i * (i - 1)) >> 1)) + i;
      offA[t][k] = ((i / 3) * XSS + (i % 3) + pos) * 4;
      offB[t][k] = ((j / 3) * XSS + (j % 3) + pos) * 4;
    }
  }

  float* orow = out + (size_t)(b * L_ + oh * WOUT) * NPAIR;
  const char* xsb = (const char*)&xs[wv][0];

  for (int s = 0; s < WOUT / 2; ++s) {        // 31 position-pairs
    f32x4* op = (f32x4*)(orow + s * (2 * NPAIR));
    const int so = s * 8;                     // +2 columns per pair
#pragma unroll
    for (int t = 0; t < 3; ++t) {
      if (t < 2 || lane < 61) {
        f32x4 v;
#pragma unroll
        for (int k = 0; k < 4; ++k) {
          float a = *(const float*)(xsb + offA[t][k] + so);
          float c = *(const float*)(xsb + offB[t][k] + so);
          v[k] = a * c;
        }
        op[lane + (t << 6)] = v;
      }
    }
  }
}

extern "C" void kernel_launch(void* const* d_in, const int* in_sizes, int n_in,
                              void* d_out, int out_size, void* d_ws, size_t ws_size,
                              hipStream_t stream) {
  const float* x = (const float*)d_in[0];
  float* out = (float*)d_out;
  localde_kernel<<<(B_ * HOUT) / 4, 256, 0, stream>>>(x, out);  // 496 blocks
}